// Round 18
// baseline (102.013 us; speedup 1.0000x reference)
//
#include <hip/hip_runtime.h>

// Problem constants (fixed by reference)
constexpr int Bn = 4, Cn = 64, Hn = 192, Wn = 640, HW = Hn * Wn;
constexpr int TH = 8, TW = 64;            // output tile per block
constexpr int SH = TH + 4;                // 12 tile+halo rows
constexpr int SW = TW + 4;                // 68
constexpr int NS = SH * SW;               // 816
constexpr int NP = NS / 2;                // 408 staging pairs
constexpr int PPR = SW / 2;               // 34 pairs per row
constexpr int NT = 384;                   // 6 waves: C-phase 89% thread-active
constexpr int CH = 4;                     // channels staged per chunk
constexpr int NCHUNK = Cn / CH;           // 16
constexpr int DR = SH - 2;                // 10 forward-dot rows
constexpr int ND = DR * SW;               // 680 forward-domain pixels
constexpr int NPAIR = DR * PPR;           // 340 pair threads (horizontal pairs)
constexpr int ARENA = 12 * ND;            // 8160 floats = 32.6 KB

// Relaxed barrier (T4): ds-writes visible via lgkmcnt(0); global loads stay
// in flight across the barrier (no vmcnt(0) drain, unlike __syncthreads).
#define SYNC_RELAXED() do {                                   \
    asm volatile("s_waitcnt lgkmcnt(0)" ::: "memory");        \
    __builtin_amdgcn_s_barrier();                             \
    asm volatile("" ::: "memory");                            \
} while (0)

// NOTE: min-waves-per-EU > 4 spills (R11). Keep 4 (VGPR cap 128).
__global__ __launch_bounds__(NT, 4) void guide_triplet_kernel(
    const float* __restrict__ pred,
    const int*   __restrict__ target,
    float* __restrict__ out)
{
    __shared__ float arena[ARENA];
    __shared__ float invnS[NS + 4];   // +4 pad: benign OOB publish reads
    __shared__ int   lblS[NS];

    const int x0 = blockIdx.x * TW;
    const int y0 = blockIdx.y * TH;
    const int b  = blockIdx.z;

    const int tid = threadIdx.x;

    // ---- staging: pair p0 = tid (all), pair p1 = tid+384 (tid < 24) ----
    const int p0 = tid, p1 = tid + NT;
    const bool has1 = (p1 < NP);              // tid < 24
    const int sr0 = p0 / PPR, sc0 = p0 - sr0 * PPR;
    const int sr1 = p1 / PPR, sc1 = p1 - sr1 * PPR;
    const int gy0 = y0 + sr0 - 2, gx0 = x0 + 2 * sc0 - 2;
    const int gy1 = y0 + sr1 - 2, gx1 = x0 + 2 * sc1 - 2;
    const bool ok0 = (gy0 >= 0) && (gy0 < Hn) && (gx0 >= 0) && (gx0 + 1 < Wn);
    const bool ok1 = has1 && (gy1 >= 0) && (gy1 < Hn) && (gx1 >= 0) && (gx1 + 1 < Wn);
    const int go0 = gy0 * Wn + gx0;
    const int go1 = gy1 * Wn + gx1;

    // ---- labels once (pad = -1) ----
    {
        const int* tb = target + b * HW;
        int lx = -1, ly = -1;
        if (ok0) { const int2 L = *reinterpret_cast<const int2*>(tb + go0); lx = L.x; ly = L.y; }
        lblS[2 * p0]     = lx;
        lblS[2 * p0 + 1] = ly;
        if (has1) {
            int mx = -1, my = -1;
            if (ok1) { const int2 L = *reinterpret_cast<const int2*>(tb + go1); mx = L.x; my = L.y; }
            lblS[2 * p1]     = mx;
            lblS[2 * p1 + 1] = my;
        }
    }
    if (tid < 4) invnS[NS + tid] = 1.0f;      // init pad

    // ---- HORIZONTAL pair mapping: thread -> pixels (pr, 2pj),(pr, 2pj+1) ----
    const bool isPair = (tid < NPAIR);        // 340/384 = 89% active
    const int pr = tid / PPR;         // 0..9
    const int pj = tid - pr * PPR;    // 0..33

    float ssx0 = 0.f, ssy0 = 0.f, ssx1 = 0.f, ssy1 = 0.f;
    float accA[12], accB[12];
    #pragma unroll
    for (int i = 0; i < 12; ++i) { accA[i] = 0.0f; accB[i] = 0.0f; }

    const float* predb = pred + (size_t)b * Cn * HW;

    float2 ldA[CH], ldB[CH];          // slot-0 depth-2 prefetch
    float2 ldA2[CH], ldB2[CH];        // slot-1 (only 24 threads use it)

#define LOADCHUNK(DST, DST2, CHUNK) do {                                    \
    _Pragma("unroll")                                                       \
    for (int cc = 0; cc < CH; ++cc) {                                       \
        const float* pc_ = predb + (size_t)((CHUNK) * CH + cc) * HW;        \
        float2 v = make_float2(0.f, 0.f), w = make_float2(0.f, 0.f);        \
        if (ok0) v = *reinterpret_cast<const float2*>(pc_ + go0);           \
        if (ok1) w = *reinterpret_cast<const float2*>(pc_ + go1);           \
        DST[cc] = v; DST2[cc] = w;                                          \
    } } while (0)

#define BODY(K, LD, LD2, KP2) {                                             \
    float* sb = arena + ((K) & 1) * (CH * NS);                              \
    /* W(K): regs -> LDS (ds_write_b64), fold sumsq */                      \
    _Pragma("unroll")                                                       \
    for (int cc = 0; cc < CH; ++cc) {                                       \
        const float2 v = LD[cc];                                            \
        *reinterpret_cast<float2*>(&sb[cc * NS + 2 * p0]) = v;              \
        ssx0 = fmaf(v.x, v.x, ssx0);                                        \
        ssy0 = fmaf(v.y, v.y, ssy0);                                        \
        if (has1) {                                                         \
            const float2 w = LD2[cc];                                       \
            *reinterpret_cast<float2*>(&sb[cc * NS + 2 * p1]) = w;          \
            ssx1 = fmaf(w.x, w.x, ssx1);                                    \
            ssy1 = fmaf(w.y, w.y, ssy1);                                    \
        } }                                                                 \
    SYNC_RELAXED();                                                         \
    /* L(K+2): depth-2 prefetch, in flight across relaxed barriers */       \
    if ((KP2) < NCHUNK) LOADCHUNK(LD, LD2, KP2);                            \
    /* C(K): horizontal pair - 16 words in 8 aligned ds_read_b64 + 24 FMA */\
    if (isPair) {                                                           \
        _Pragma("unroll")                                                   \
        for (int cc = 0; cc < CH; ++cc) {                                   \
            const float* s0 = sb + cc * NS + pr * SW + 2 * pj;              \
            const float r00 = s0[0], r01 = s0[1], r02 = s0[2], r03 = s0[3]; \
            const float* s1 = s0 + (SW - 2);                                \
            const float r10 = s1[0], r11 = s1[1], r12 = s1[2],              \
                        r13 = s1[3], r14 = s1[4], r15 = s1[5];              \
            const float* s2 = s1 + SW;                                      \
            const float r20 = s2[0], r21 = s2[1], r22 = s2[2],              \
                        r23 = s2[3], r24 = s2[4], r25 = s2[5];              \
            accA[0]  = fmaf(r00, r01, accA[0]);                             \
            accA[1]  = fmaf(r00, r02, accA[1]);                             \
            accA[2]  = fmaf(r00, r10, accA[2]);                             \
            accA[3]  = fmaf(r00, r11, accA[3]);                             \
            accA[4]  = fmaf(r00, r12, accA[4]);                             \
            accA[5]  = fmaf(r00, r13, accA[5]);                             \
            accA[6]  = fmaf(r00, r14, accA[6]);                             \
            accA[7]  = fmaf(r00, r20, accA[7]);                             \
            accA[8]  = fmaf(r00, r21, accA[8]);                             \
            accA[9]  = fmaf(r00, r22, accA[9]);                             \
            accA[10] = fmaf(r00, r23, accA[10]);                            \
            accA[11] = fmaf(r00, r24, accA[11]);                            \
            accB[0]  = fmaf(r01, r02, accB[0]);                             \
            accB[1]  = fmaf(r01, r03, accB[1]);                             \
            accB[2]  = fmaf(r01, r11, accB[2]);                             \
            accB[3]  = fmaf(r01, r12, accB[3]);                             \
            accB[4]  = fmaf(r01, r13, accB[4]);                             \
            accB[5]  = fmaf(r01, r14, accB[5]);                             \
            accB[6]  = fmaf(r01, r15, accB[6]);                             \
            accB[7]  = fmaf(r01, r21, accB[7]);                             \
            accB[8]  = fmaf(r01, r22, accB[8]);                             \
            accB[9]  = fmaf(r01, r23, accB[9]);                             \
            accB[10] = fmaf(r01, r24, accB[10]);                            \
            accB[11] = fmaf(r01, r25, accB[11]);                            \
        } } }

    LOADCHUNK(ldA, ldA2, 0);
    LOADCHUNK(ldB, ldB2, 1);

    for (int chunk = 0; chunk < NCHUNK; chunk += 2) {
        BODY(chunk,     ldA, ldA2, chunk + 2)
        BODY(chunk + 1, ldB, ldB2, chunk + 3)
    }

    // ---- inverse norms ----
    invnS[2 * p0]     = 1.0f / fmaxf(sqrtf(ssx0), 1e-12f);
    invnS[2 * p0 + 1] = 1.0f / fmaxf(sqrtf(ssy0), 1e-12f);
    if (has1) {
        invnS[2 * p1]     = 1.0f / fmaxf(sqrtf(ssx1), 1e-12f);
        invnS[2 * p1 + 1] = 1.0f / fmaxf(sqrtf(ssy1), 1e-12f);
    }
    __syncthreads();   // full drain: C reads done; invn visible; arena reusable

    constexpr int DIRD[12] = {1, 2, SW - 2, SW - 1, SW, SW + 1, SW + 2,
                              2 * SW - 2, 2 * SW - 1, 2 * SW, 2 * SW + 1, 2 * SW + 2};

    // ---- publish AFFINITY planes (each pair affinity computed ONCE) ----
    if (isPair) {
        const int qA = pr * SW + 2 * pj;
        const int qB = qA + 1;
        const float icA = invnS[qA];
        const float icB = invnS[qB];
        #pragma unroll
        for (int k = 0; k < 12; ++k) {
            const int dq = DIRD[k];
            const float simA = accA[k] * icA * invnS[qA + dq];
            const float simB = accB[k] * icB * invnS[qB + dq];
            arena[k * ND + qA] = sqrtf(fmaxf(1e-9f, fmaf(-2.0f, simA, 2.0f)));
            arena[k * ND + qB] = sqrtf(fmaxf(1e-9f, fmaf(-2.0f, simB, 2.0f)));
        }
    }
    __syncthreads();

    // ---- epilogue: 512 outputs over 384 threads ----
    #pragma unroll
    for (int half = 0; half < 2; ++half) {
        const int e = tid + half * NT;            // 0..767, use e < 512
        if (half == 1 && e >= 512) break;
        const int row = e >> 6, col = e & 63;
        const int qp  = (2 + row) * SW + (2 + col);
        const int lc  = lblS[qp];
        float tot = 0.0f, ps = 0.0f, pn = 0.0f;
        #pragma unroll
        for (int k = 0; k < 12; ++k) {
            const int dq = DIRD[k];
            const float affF = arena[k * ND + qp];
            const float affB = arena[k * ND + qp - dq];
            const float mfF = (lblS[qp + dq] == lc) ? 1.0f : 0.0f;
            const float mfB = (lblS[qp - dq] == lc) ? 1.0f : 0.0f;
            tot += affF + affB;
            pn += mfF + mfB;
            ps = fmaf(mfF, affF, fmaf(mfB, affB, ps));
        }
        const float pos_num = pn + 1.0f;
        const float pos_sum = ps + 3.16227766e-5f;   // self: aff=sqrt(1e-9)
        const float neg_num = 24.0f - pn;
        const float neg_sum = tot - ps;
        const bool boundary = (pos_num >= 4.0f) && (neg_num >= 4.0f);
        const float tri = fmaxf(0.0f,
            pos_sum / pos_num - neg_sum / fmaxf(neg_num, 1e-12f) + 0.3f);
        out[((size_t)b * Hn + (y0 + row)) * Wn + (x0 + col)] = boundary ? tri : 0.0f;
    }
}

extern "C" void kernel_launch(void* const* d_in, const int* in_sizes, int n_in,
                              void* d_out, int out_size, void* d_ws, size_t ws_size,
                              hipStream_t stream) {
    const float* pred   = (const float*)d_in[0];
    const int*   target = (const int*)d_in[1];
    float*       out    = (float*)d_out;
    dim3 grid(Wn / TW, Hn / TH, Bn);   // 10 x 24 x 4 = 960 blocks
    guide_triplet_kernel<<<grid, NT, 0, stream>>>(pred, target, out);
}